// Round 2
// baseline (155.589 us; speedup 1.0000x reference)
//
#include <hip/hip_runtime.h>

#define NB 128
#define NTOK 201

// One block per (e, batch), e in 0..4. Threads = output columns j (M <= 197 < 256).
// u^T <- u^T * att_e[l] for l = 10..0, u0 = row 0 of att_e[11].
// att_e gathers token index e plus window [lo, hi) on both rows and cols.
__global__ __launch_bounds__(256) void part_att_chain_kernel(
    const float* __restrict__ x, float* __restrict__ out)
{
    const int bid = blockIdx.x;
    const int e   = bid >> 7;      // 0..4 (token index)
    const int b   = bid & 127;

    int lo, hi;
    if      (e == 0) { lo = 5;   hi = 201; }
    else if (e == 1) { lo = 5;   hi = 201; }
    else if (e == 2) { lo = 5;   hi = 103; }
    else if (e == 3) { lo = 54;  hi = 152; }
    else             { lo = 103; hi = 201; }
    const int M = 1 + (hi - lo);

    const int tid = threadIdx.x;
    const bool active = tid < M;
    // column in x-space for this thread's att column
    const int c = (tid == 0) ? e : (lo + tid - 1);

    __shared__ float ubuf[2][208];

    const size_t plane = (size_t)NTOK * NTOK;
    const float* xb = x + (size_t)b * plane;        // x[l][b] = xb + (l*NB)*plane

    // init: u[j] = x[11, b, e, c(j)]  (row 0 of att[11] is x row e, gathered cols)
    if (active)
        ubuf[0][tid] = xb[(size_t)(11 * NB) * plane + (size_t)e * NTOK + c];
    __syncthreads();

    int cur = 0;
    for (int l = 10; l >= 0; --l) {
        const float* A = xb + (size_t)(l * NB) * plane;   // x[l][b]
        float acc = 0.0f;
        if (active) {
            const float* u = ubuf[cur];
            // i = 0 : att row 0 = x row e
            acc = u[0] * A[(size_t)e * NTOK + c];
            // i = 1..M-1 : x rows lo..hi-1
            const float* rp = A + (size_t)lo * NTOK + c;
            float a0 = 0.f, a1 = 0.f, a2 = 0.f, a3 = 0.f;
            int i = 1;
            for (; i + 3 < M; i += 4) {
                a0 += u[i]     * rp[0];
                a1 += u[i + 1] * rp[NTOK];
                a2 += u[i + 2] * rp[2 * NTOK];
                a3 += u[i + 3] * rp[3 * NTOK];
                rp += 4 * NTOK;
            }
            for (; i < M; ++i) { a0 += u[i] * rp[0]; rp += NTOK; }
            acc += (a0 + a1) + (a2 + a3);
        }
        // write to the other buffer; single barrier publishes it and also
        // guarantees everyone is done reading ubuf[cur] before reuse.
        if (active) ubuf[1 - cur][tid] = acc;
        __syncthreads();
        cur = 1 - cur;
    }

    // max + argmax over j in [1, M-1] of ubuf[cur], first-occurrence ties.
    __shared__ float rv[256];
    __shared__ int   ri[256];
    float v = -INFINITY;
    int   idx = 0x7fffffff;
    if (tid >= 1 && tid < M) { v = ubuf[cur][tid]; idx = tid; }
    rv[tid] = v; ri[tid] = idx;
    __syncthreads();
    for (int s = 128; s > 0; s >>= 1) {
        if (tid < s) {
            float v2 = rv[tid + s]; int i2 = ri[tid + s];
            if (v2 > rv[tid] || (v2 == rv[tid] && i2 < ri[tid])) {
                rv[tid] = v2; ri[tid] = i2;
            }
        }
        __syncthreads();
    }

    if (tid == 0) {
        // out layout: [5,128,1] float max_p, then [5,128,1] indices (as float).
        // SPECS[e][2] == lo for every e; sliced-row index = j-1.
        out[e * NB + b]       = rv[0];
        out[640 + e * NB + b] = (float)((ri[0] - 1) + lo);
    }
}

extern "C" void kernel_launch(void* const* d_in, const int* in_sizes, int n_in,
                              void* d_out, int out_size, void* d_ws, size_t ws_size,
                              hipStream_t stream) {
    (void)in_sizes; (void)n_in; (void)d_ws; (void)ws_size; (void)out_size;
    const float* x = (const float*)d_in[0];
    float* out = (float*)d_out;
    // 5 e values x 128 batches
    part_att_chain_kernel<<<dim3(640), dim3(256), 0, stream>>>(x, out);
}

// Round 3
// 69.768 us; speedup vs baseline: 2.2301x; 2.2301x over previous
//
#include <hip/hip_runtime.h>

#define NB 128
#define NTOK 201

// One block per (e, batch), e in 0..4. 1024 threads = COLS columns x RG row-groups.
// u^T <- u^T * att_e[l] for l = 10..0, u0 = row 0 of att_e[11].
__global__ __launch_bounds__(1024) void part_att_chain_kernel(
    const float* __restrict__ x, float* __restrict__ out)
{
    const int bid = blockIdx.x;
    const int e   = bid >> 7;      // 0..4 (token index)
    const int b   = bid & 127;

    int lo, hi;
    if      (e == 0) { lo = 5;   hi = 201; }
    else if (e == 1) { lo = 5;   hi = 201; }
    else if (e == 2) { lo = 5;   hi = 103; }
    else if (e == 3) { lo = 54;  hi = 152; }
    else             { lo = 103; hi = 201; }
    const int M = 1 + (hi - lo);

    const int tid = threadIdx.x;
    // geometry: 256 cols x 4 row-groups for M=197; 128 cols x 8 row-groups for M=99
    const int cshift = (M > 128) ? 8 : 7;
    const int COLS   = 1 << cshift;
    const int RG     = 1024 >> cshift;
    const int j      = tid & (COLS - 1);
    const int rg     = tid >> cshift;

    const bool colActive = (j < M);
    const int c = (j == 0) ? e : (lo + j - 1);     // x-space column for att col j

    __shared__ float ubuf[2][208];
    __shared__ float part[1024];
    __shared__ float rv[256];
    __shared__ int   ri[256];

    const size_t plane = (size_t)NTOK * NTOK;
    const float* xb = x + (size_t)b * plane;       // x[l][b] = xb + (l*NB)*plane

    // init: u[j] = x[11, b, e, c(j)]  (row 0 of att[11])
    if (tid < M) {
        const int c0 = (tid == 0) ? e : (lo + tid - 1);
        ubuf[0][tid] = xb[(size_t)(11 * NB) * plane + (size_t)e * NTOK + c0];
    }
    __syncthreads();

    int cur = 0;
    for (int l = 10; l >= 0; --l) {
        const float* A = xb + (size_t)(l * NB) * plane;   // x[l][b]
        float a0 = 0.f, a1 = 0.f, a2 = 0.f, a3 = 0.f;
        if (colActive) {
            const float* u = ubuf[cur];
            int i = rg;
            if (rg == 0) {                     // att row 0 = x row e
                a0 = u[0] * A[(size_t)e * NTOK + c];
                i = RG;
            }
            // att rows i>=1 -> x rows lo+i-1
            const float* rp = A + (size_t)(lo + i - 1) * NTOK + c;
            const int step = RG * NTOK;
            for (; i + 3 * RG < M; i += 4 * RG) {
                a0 += u[i]          * rp[0];
                a1 += u[i +     RG] * rp[step];
                a2 += u[i + 2 * RG] * rp[2 * step];
                a3 += u[i + 3 * RG] * rp[3 * step];
                rp += 4 * step;
            }
            for (; i < M; i += RG) { a0 += u[i] * rp[0]; rp += step; }
        }
        part[tid] = (a0 + a1) + (a2 + a3);
        __syncthreads();
        if (j == tid && colActive) {           // rg == 0 threads reduce
            float s = part[tid];
            for (int g = 1; g < RG; ++g) s += part[g * COLS + tid];
            ubuf[1 - cur][tid] = s;
        }
        __syncthreads();
        cur = 1 - cur;
    }

    // max + argmax over j in [1, M-1] of ubuf[cur], first-occurrence ties.
    if (tid < 256) {
        float v = -INFINITY;
        int   idx = 0x7fffffff;
        if (tid >= 1 && tid < M) { v = ubuf[cur][tid]; idx = tid; }
        rv[tid] = v; ri[tid] = idx;
    }
    __syncthreads();
    for (int s = 128; s > 0; s >>= 1) {
        if (tid < s) {
            float v2 = rv[tid + s]; int i2 = ri[tid + s];
            if (v2 > rv[tid] || (v2 == rv[tid] && i2 < ri[tid])) {
                rv[tid] = v2; ri[tid] = i2;
            }
        }
        __syncthreads();
    }

    if (tid == 0) {
        // out layout: [5,128,1] float max_p, then [5,128,1] indices (as float).
        // SPECS[e][2] == lo for every e; sliced-row index = j-1.
        out[e * NB + b]       = rv[0];
        out[640 + e * NB + b] = (float)((ri[0] - 1) + lo);
    }
}

extern "C" void kernel_launch(void* const* d_in, const int* in_sizes, int n_in,
                              void* d_out, int out_size, void* d_ws, size_t ws_size,
                              hipStream_t stream) {
    (void)in_sizes; (void)n_in; (void)d_ws; (void)ws_size; (void)out_size;
    const float* x = (const float*)d_in[0];
    float* out = (float*)d_out;
    // 5 e values x 128 batches
    part_att_chain_kernel<<<dim3(640), dim3(1024), 0, stream>>>(x, out);
}